// Round 4
// baseline (92.287 us; speedup 1.0000x reference)
//
#include <hip/hip_runtime.h>
#include <hip/hip_bf16.h>

typedef __bf16 bf16x8 __attribute__((ext_vector_type(8)));
typedef float f32x4 __attribute__((ext_vector_type(4)));

// Pre-kernel: clusters (128x512 f32) -> bf16 in ws, plus fp32 c2[128].
__global__ __launch_bounds__(64)
void prep_clusters(const float* __restrict__ c, __bf16* __restrict__ cb,
                   float* __restrict__ c2)
{
    const int row = blockIdx.x;     // 0..127
    const int l = threadIdx.x;      // 0..63
    const float* p = c + row * 512 + l * 8;
    f32x4 u0 = *(const f32x4*)p;
    f32x4 u1 = *(const f32x4*)(p + 4);
    bf16x8 v;
    float s = 0.f;
#pragma unroll
    for (int j = 0; j < 4; ++j) {
        v[j]     = (__bf16)u0[j];
        v[4 + j] = (__bf16)u1[j];
        s += u0[j] * u0[j] + u1[j] * u1[j];
    }
    *(bf16x8*)(cb + row * 512 + l * 8) = v;
#pragma unroll
    for (int off = 32; off >= 1; off >>= 1) s += __shfl_xor(s, off);
    if (l == 0) c2[row] = s;
}

__device__ __forceinline__ void gl_lds16(const float* g, float* l)
{
    __builtin_amdgcn_global_load_lds(
        (const __attribute__((address_space(1))) void*)g,
        (__attribute__((address_space(3))) void*)l, 16, 0, 0);
}

// Wave-private pipeline: each wave owns 64 rows x 128 cols and a 2 x 8KB LDS
// double-buffer. NO s_barrier anywhere — only per-wave counted vmcnt waits, so
// waves stagger and VMEM issue stays smooth. LDS is XOR-swizzled on BOTH sides
// (pre-swizzled global source chunk for global_load_lds's linear write, and
// swizzled ds_read address): 16B chunk c at row r holds global chunk c^(r&7),
// turning the 16-way bank conflict of the 128B-stride tile into 2-way (free).
__global__ __launch_bounds__(256, 2)
void cluster_q_mfma(const float* __restrict__ x,
                    const __bf16* __restrict__ cb,
                    const float* __restrict__ c2,
                    float* __restrict__ out)
{
    __shared__ float lds[4][2][2048];   // [wave][buf][64 rows x 32 k]

    const int tid = threadIdx.x;
    const int l = tid & 63;
    const int w = tid >> 6;
    const int m = l & 15;          // fragment row (A) / col (B)
    const int g = l >> 4;          // k-group (0..3), 8 contiguous k
    const long wrow = (long)blockIdx.x * 256 + w * 64;

    f32x4 acc[4][8];
#pragma unroll
    for (int i = 0; i < 4; ++i)
#pragma unroll
        for (int j = 0; j < 8; ++j) acc[i][j] = f32x4{0.f, 0.f, 0.f, 0.f};

    float x2p[4] = {0.f, 0.f, 0.f, 0.f};

    // Staging: instruction i covers rows [i*8, i*8+8); lane handles row
    // i*8 + (l>>3), source 16B-chunk (l&7)^(l>>3)  (the pre-swizzle).
    const float* sbase = x + (wrow + (l >> 3)) * 512 + ((l & 7) ^ (l >> 3)) * 4;

    const __bf16* cbp = cb + m * 512 + g * 8;

    float c2v[8];
#pragma unroll
    for (int nb = 0; nb < 8; ++nb) c2v[nb] = c2[nb * 16 + m];

#define STAGE(BUF, K0)                                                    \
    { _Pragma("unroll")                                                   \
      for (int i_ = 0; i_ < 8; ++i_)                                      \
          gl_lds16(sbase + (long)i_ * (8 * 512) + (K0),                   \
                   &lds[w][BUF][i_ * 256]); }

    STAGE(0, 0);                          // prologue: tile 0 in flight

#pragma unroll 1
    for (int it = 0; it < 16; ++it) {
        const int cur = it & 1;
        const int kb = it * 32;

        // B fragments for this k-step (L2-resident bf16 clusters).
        bf16x8 bF[8];
#pragma unroll
        for (int nb = 0; nb < 8; ++nb)
            bF[nb] = *(const bf16x8*)(cbp + nb * (16 * 512) + kb);
        __builtin_amdgcn_sched_barrier(0);

        if (it < 15) {
            // WAR guard: prior ds_reads of the buffer we're about to overwrite.
            asm volatile("s_waitcnt lgkmcnt(0)" ::: "memory");
            __builtin_amdgcn_sched_barrier(0);
            STAGE(cur ^ 1, kb + 32);
            __builtin_amdgcn_sched_barrier(0);
            // Drain tile `it` + B; leave the 8 next-tile loads in flight.
            asm volatile("s_waitcnt vmcnt(8)" ::: "memory");
        } else {
            asm volatile("s_waitcnt vmcnt(0)" ::: "memory");
        }
        __builtin_amdgcn_sched_barrier(0);

        // Compute from LDS (swizzled read): A-frag f32 -> bf16, x2, 32 MFMA.
        bf16x8 aF[4];
#pragma unroll
        for (int rb = 0; rb < 4; ++rb) {
            const int row = m + rb * 16;
            const float* bw = &lds[w][cur][0] + row * 32;
            f32x4 u0 = *(const f32x4*)(bw + (((2 * g)     ^ (m & 7)) * 4));
            f32x4 u1 = *(const f32x4*)(bw + (((2 * g + 1) ^ (m & 7)) * 4));
#pragma unroll
            for (int j = 0; j < 4; ++j) {
                aF[rb][j]     = (__bf16)u0[j];
                aF[rb][4 + j] = (__bf16)u1[j];
                x2p[rb] += u0[j] * u0[j];
                x2p[rb] += u1[j] * u1[j];
            }
        }
#pragma unroll
        for (int rb = 0; rb < 4; ++rb)
#pragma unroll
            for (int nb = 0; nb < 8; ++nb)
                acc[rb][nb] = __builtin_amdgcn_mfma_f32_16x16x32_bf16(
                    aF[rb], bF[nb], acc[rb][nb], 0, 0, 0);
    }
#undef STAGE

    // Complete x2 across the 4 k-groups (lanes m, m+16, m+32, m+48).
#pragma unroll
    for (int rb = 0; rb < 4; ++rb) {
        x2p[rb] += __shfl_xor(x2p[rb], 16);
        x2p[rb] += __shfl_xor(x2p[rb], 32);
    }

    // Epilogue. C/D layout: col = m, row(within 16-block) = g*4 + r.
#pragma unroll
    for (int rb = 0; rb < 4; ++rb) {
        float x2r[4], rs[4];
#pragma unroll
        for (int r = 0; r < 4; ++r) {
            x2r[r] = __shfl(x2p[rb], g * 4 + r);
            rs[r] = 0.f;
        }
#pragma unroll
        for (int nb = 0; nb < 8; ++nb) {
#pragma unroll
            for (int r = 0; r < 4; ++r) {
                float d2 = x2r[r] + c2v[nb] - 2.f * acc[rb][nb][r];
                d2 = fmaxf(d2, 0.f);
                float q = 1.f / (1.f + d2);   // ALPHA=1 -> exponent is 1
                acc[rb][nb][r] = q;
                rs[r] += q;
            }
        }
#pragma unroll
        for (int r = 0; r < 4; ++r) {
            rs[r] += __shfl_xor(rs[r], 1);
            rs[r] += __shfl_xor(rs[r], 2);
            rs[r] += __shfl_xor(rs[r], 4);
            rs[r] += __shfl_xor(rs[r], 8);
            rs[r] = 1.f / rs[r];
        }
        const long orow = wrow + rb * 16 + g * 4;
#pragma unroll
        for (int nb = 0; nb < 8; ++nb) {
#pragma unroll
            for (int r = 0; r < 4; ++r) {
                out[(orow + r) * 128 + nb * 16 + m] = acc[rb][nb][r] * rs[r];
            }
        }
    }
}

extern "C" void kernel_launch(void* const* d_in, const int* in_sizes, int n_in,
                              void* d_out, int out_size, void* d_ws, size_t ws_size,
                              hipStream_t stream)
{
    const float* x = (const float*)d_in[0];
    const float* c = (const float*)d_in[1];
    float* out = (float*)d_out;

    float*  c2ws = (float*)d_ws;                        // 128 floats
    __bf16* cbws = (__bf16*)((char*)d_ws + 1024);       // 128x512 bf16 = 128 KB

    hipLaunchKernelGGL(prep_clusters, dim3(128), dim3(64), 0, stream, c, cbws, c2ws);

    const int N = in_sizes[0] / 512;                    // 131072 rows
    dim3 grid(N / 256), block(256);                     // 512 blocks = 2/CU
    hipLaunchKernelGGL(cluster_q_mfma, grid, block, 0, stream, x, cbws, c2ws, out);
}